// Round 6
// baseline (101.773 us; speedup 1.0000x reference)
//
#include <hip/hip_runtime.h>
#include <hip/hip_bf16.h>
#include <math.h>

#define BATCH 8
#define SEQ   2048
#define DIM   64
#define NEGC  (-1e9f)
#define SPLIT 4
#define TPB   8            // tiles per block = 32 / SPLIT

typedef short short8  __attribute__((ext_vector_type(8)));
typedef float f32x4   __attribute__((ext_vector_type(4)));
typedef float f32x16  __attribute__((ext_vector_type(16)));

#define MFMA32(a, b, c) __builtin_amdgcn_mfma_f32_32x32x16_bf16((a), (b), (c), 0, 0, 0)

__device__ __forceinline__ ushort f2bf(float x) {   // fp32 -> bf16 bits, RNE
    uint u = __float_as_uint(x);
    uint r = (u + 0x7fffu + ((u >> 16) & 1u)) >> 16;
    return (ushort)r;
}
__device__ __forceinline__ float bf2f(ushort h) {
    return __uint_as_float(((uint)h) << 16);
}

// ---------------------------------------------------------------------------
// ws layout:
//   [0, 4MB):    KV frag images, per (b,tile) 16384 B = [Kh 8KB][Vf 8KB]
//     Kh row r (8 bf16): r=(mt*4+kc)*64+L -> K[key=mt*32+(L&31)][d=kc*16+(L>>5)*8+j]
//     Vf row r:          r=(dt*4+kc)*64+L -> V[key=kc*16+(L>>5)*8+j][d=dt*32+(L&31)]
//   [4MB, 20MB): PO partials [s][b][q 2048][d 64] f32
//   [20MB, ..):  ML partials [s][b][q 2048] float2 {m, l}
// ---------------------------------------------------------------------------
__global__ __launch_bounds__(256)
void prep_kv(const float* __restrict__ K, const float* __restrict__ V,
             const float* __restrict__ MV, ushort* __restrict__ ws) {
    __shared__ float raw[64 * 68];
    const int t    = threadIdx.x;
    const int b    = blockIdx.x >> 5;
    const int tile = blockIdx.x & 31;
    const float* Kb  = K  + ((size_t)b * SEQ + tile * 64) * DIM;
    const float* Vb  = V  + ((size_t)b * SEQ + tile * 64) * DIM;
    const float* MVb = MV + (size_t)b * SEQ + tile * 64;
    ushort* wsI = ws + (size_t)(b * 32 + tile) * 8192;

    // ---- K ----
#pragma unroll
    for (int u = 0; u < 4; u++) {
        int f = t + 256 * u, key = f >> 4, d4 = (f & 15) * 4;
        *(float4*)&raw[key * 68 + d4] = *(const float4*)(Kb + (size_t)f * 4);
    }
    __syncthreads();
#pragma unroll
    for (int u = 0; u < 2; u++) {
        int r = t + 256 * u;
        int mt = r >> 8, kc = (r >> 6) & 3, L = r & 63;
        int key = mt * 32 + (L & 31), d0 = kc * 16 + (L >> 5) * 8;
        float4 x0 = *(float4*)&raw[key * 68 + d0];
        float4 x1 = *(float4*)&raw[key * 68 + d0 + 4];
        float xs[8] = {x0.x, x0.y, x0.z, x0.w, x1.x, x1.y, x1.z, x1.w};
        short8 hv;
#pragma unroll
        for (int j = 0; j < 8; j++) hv[j] = (short)f2bf(xs[j]);
        *(short8*)(wsI + r * 8) = hv;
    }
    __syncthreads();

    // ---- V (mask_v folded) ----
#pragma unroll
    for (int u = 0; u < 4; u++) {
        int f = t + 256 * u, key = f >> 4, d4 = (f & 15) * 4;
        float4 x = *(const float4*)(Vb + (size_t)f * 4);
        float mv = MVb[key];
        x.x *= mv; x.y *= mv; x.z *= mv; x.w *= mv;
        *(float4*)&raw[key * 68 + d4] = x;
    }
    __syncthreads();
#pragma unroll
    for (int u = 0; u < 2; u++) {
        int r = t + 256 * u;
        int dt = r >> 8, kc = (r >> 6) & 3, L = r & 63;
        int d = dt * 32 + (L & 31), k0 = kc * 16 + (L >> 5) * 8;
        short8 ov;
#pragma unroll
        for (int j = 0; j < 8; j++) ov[j] = (short)f2bf(raw[(k0 + j) * 68 + d]);
        *(short8*)(wsI + 4096 + r * 8) = ov;
    }
}

// ---------------------------------------------------------------------------
// Main: 256 thr = 4 waves (2 qg x 2 kh), 64 q/block, 4-way split-K across
// blocks (8 k-tiles each). Grid 1024 -> 4 blocks/CU (LDS 32.8KB, VGPR<=128).
// 32x32x16 MFMA. Merge scratch ALIASES Stage (only used after last barrier).
// ---------------------------------------------------------------------------
__global__ __launch_bounds__(256, 4)
void attn_main(const float* __restrict__ Q, const float* __restrict__ MQ,
               const float* __restrict__ MK, const ushort* __restrict__ ws,
               float* __restrict__ PO, float* __restrict__ ML) {
    __shared__ __align__(16) ushort Stage[2][8192];   // [Kh 4096 us | Vf 4096 us] x2

    const int t    = threadIdx.x;
    const int w    = t >> 6;
    const int lane = t & 63;
    const int h    = lane >> 5;
    const int lm   = lane & 31;
    const int qg   = w & 1;
    const int kh   = w >> 1;

    const int s  = blockIdx.x & 3;          // k-split
    const int qb = blockIdx.x >> 2;
    const int b  = qb >> 5;
    const int qt = qb & 31;
    const int q  = qt * 64 + qg * 32 + lm;

    const float*  MKb  = MK + (size_t)b * SEQ;
    const ushort* wsKV = ws + (size_t)b * 32 * 8192;

    // ---- Q fragments (B-operand), hi/lo, pre-scaled by 1/8 ----
    short8 qh[4], ql[4];
    {
        const float* Qr = Q + ((size_t)b * SEQ + q) * DIM;
#pragma unroll
        for (int kc = 0; kc < 4; kc++) {
            const float* p = Qr + kc * 16 + h * 8;
            float4 x0 = *(const float4*)p;
            float4 x1 = *(const float4*)(p + 4);
            float xs[8] = {x0.x, x0.y, x0.z, x0.w, x1.x, x1.y, x1.z, x1.w};
#pragma unroll
            for (int j = 0; j < 8; j++) {
                float v   = xs[j] * 0.125f;
                ushort hi = f2bf(v);
                ql[kc][j] = (short)f2bf(v - bf2f(hi));
                qh[kc][j] = (short)hi;
            }
        }
    }
    const float mq   = MQ[(size_t)b * SEQ + q];
    const float apen = NEGC * mq;

    float m = -1e30f, l = 0.0f;
    f32x16 ot0, ot1;
#pragma unroll
    for (int i = 0; i < 16; i++) { ot0[i] = 0.0f; ot1[i] = 0.0f; }

    // ---- stage first tile ----
    {
        const ushort* src = wsKV + (size_t)(s * TPB) * 8192;
#pragma unroll
        for (int u = 0; u < 4; u++) {
            const int off = (u * 256 + w * 64 + lane) * 8;
            __builtin_amdgcn_global_load_lds(
                (const __attribute__((address_space(1))) void*)(src + off),
                (__attribute__((address_space(3))) void*)(&Stage[0][0] + off),
                16, 0, 0);
        }
    }
    __syncthreads();

    f32x4 mk[4];
#pragma unroll
    for (int v = 0; v < 4; v++)
        mk[v] = *(const f32x4*)(MKb + (s * TPB) * 64 + kh * 32 + v * 8 + h * 4);

#pragma unroll 1
    for (int tt = 0; tt < TPB; tt++) {
        const ushort* cur = &Stage[tt & 1][0];

        // ---- prefetch next tile (no wait) ----
        if (tt + 1 < TPB) {
            const ushort* src = wsKV + (size_t)(s * TPB + tt + 1) * 8192;
            ushort* dst = &Stage[(tt + 1) & 1][0];
#pragma unroll
            for (int u = 0; u < 4; u++) {
                const int off = (u * 256 + w * 64 + lane) * 8;
                __builtin_amdgcn_global_load_lds(
                    (const __attribute__((address_space(1))) void*)(src + off),
                    (__attribute__((address_space(3))) void*)(dst + off),
                    16, 0, 0);
            }
        }
        f32x4 nmk[4];
#pragma unroll
        for (int v = 0; v < 4; v++) nmk[v] = mk[v];
        if (tt + 1 < TPB) {
            const float* mkp = MKb + (s * TPB + tt + 1) * 64 + kh * 32 + h * 4;
#pragma unroll
            for (int v = 0; v < 4; v++) nmk[v] = *(const f32x4*)(mkp + v * 8);
        }

        // ---- QK^T: 32q x 32k x 64d, K hi, Q hi/lo ----
        f32x16 st;
#pragma unroll
        for (int i = 0; i < 16; i++) st[i] = 0.0f;
#pragma unroll
        for (int kc = 0; kc < 4; kc++) {
            short8 a = *(const short8*)&cur[((kh * 4 + kc) * 64 + lane) * 8];
            st = MFMA32(a, qh[kc], st);
            st = MFMA32(a, ql[kc], st);
        }

        // ---- online softmax: lane holds 16 keys of its query column ----
        float sv[16];
#pragma unroll
        for (int v = 0; v < 4; v++)
#pragma unroll
            for (int c = 0; c < 4; c++)
                sv[v * 4 + c] = st[v * 4 + c] + (NEGC - apen * mk[v][c]);
        float cm = sv[0];
#pragma unroll
        for (int i = 1; i < 16; i++) cm = fmaxf(cm, sv[i]);
        cm = fmaxf(cm, __shfl_xor(cm, 32));
        float nm    = fmaxf(m, cm);
        float alpha = __expf(m - nm);
        m = nm;

        float p[16], cs = 0.0f;
#pragma unroll
        for (int i = 0; i < 16; i++) { p[i] = __expf(sv[i] - nm); cs += p[i]; }
        cs += __shfl_xor(cs, 32);
        l   = l * alpha + cs;
        ot0 *= alpha; ot1 *= alpha;

        // ---- P: C-layout -> B-frags via half-wave exchange ----
        uint g[4][2], x[4][2];
#pragma unroll
        for (int v = 0; v < 4; v++) {
            __hip_bfloat162 c0 = __float22bfloat162_rn(make_float2(p[v*4+0], p[v*4+1]));
            __hip_bfloat162 c1 = __float22bfloat162_rn(make_float2(p[v*4+2], p[v*4+3]));
            __builtin_memcpy(&g[v][0], &c0, 4);
            __builtin_memcpy(&g[v][1], &c1, 4);
            x[v][0] = (uint)__shfl_xor((int)g[v][0], 32);
            x[v][1] = (uint)__shfl_xor((int)g[v][1], 32);
        }
        uint pbw[2][4];
        pbw[0][0] = h ? x[1][0] : g[0][0];
        pbw[0][1] = h ? x[1][1] : g[0][1];
        pbw[0][2] = h ? g[1][0] : x[0][0];
        pbw[0][3] = h ? g[1][1] : x[0][1];
        pbw[1][0] = h ? x[3][0] : g[2][0];
        pbw[1][1] = h ? x[3][1] : g[2][1];
        pbw[1][2] = h ? g[3][0] : x[2][0];
        pbw[1][3] = h ? g[3][1] : x[2][1];

        // ---- PV: Oᵀ = Vᵀ·Pᵀ over this wave's 32 keys ----
#pragma unroll
        for (int c = 0; c < 2; c++) {
            short8 pb;
            __builtin_memcpy(&pb, &pbw[c][0], 16);
            short8 v0 = *(const short8*)&cur[4096 + ((0 * 4 + kh * 2 + c) * 64 + lane) * 8];
            short8 v1 = *(const short8*)&cur[4096 + ((1 * 4 + kh * 2 + c) * 64 + lane) * 8];
            ot0 = MFMA32(v0, pb, ot0);
            ot1 = MFMA32(v1, pb, ot1);
        }

#pragma unroll
        for (int v = 0; v < 4; v++) mk[v] = nmk[v];
        __syncthreads();
    }

    // ---- intra-block kh merge (scratch aliases Stage; stride 36 = 16B mult) ----
    float* MscF = (float*)&Stage[0][0];
    if (kh == 1) {
        float* sc = MscF + (qg * 64 + lane) * 36;
#pragma unroll
        for (int i = 0; i < 16; i++) { sc[i] = ot0[i]; sc[16 + i] = ot1[i]; }
        sc[32] = m;
        sc[33] = l;
    }
    __syncthreads();
    if (kh == 0) {
        const float* sc = MscF + (qg * 64 + lane) * 36;
        float mb = sc[32], lb = sc[33];
        float nm = fmaxf(m, mb);
        float fa = __expf(m - nm);
        float fb = __expf(mb - nm);
        float lt = l * fa + lb * fb;

        float* po = PO + (((size_t)(s * 8 + b) * SEQ) + qt * 64 + qg * 32 + lm) * 64;
#pragma unroll
        for (int dt = 0; dt < 2; dt++) {
            const f32x16& o = dt ? ot1 : ot0;
#pragma unroll
            for (int rq = 0; rq < 4; rq++) {
                f32x4 r;
#pragma unroll
                for (int c = 0; c < 4; c++)
                    r[c] = o[rq * 4 + c] * fa + sc[dt * 16 + rq * 4 + c] * fb;
                *(f32x4*)(po + dt * 32 + rq * 8 + h * 4) = r;
            }
        }
        if (h == 0) {
            float2* ml2 = (float2*)ML;
            ml2[((size_t)(s * 8 + b) * SEQ) + qt * 64 + qg * 32 + lm] =
                make_float2(nm, lt);
        }
    }
}

// ---------------------------------------------------------------------------
// Cross-block 4-way split-K merge.
// ---------------------------------------------------------------------------
__global__ __launch_bounds__(256)
void merge_o(const float* __restrict__ PO, const float* __restrict__ ML,
             float* __restrict__ O) {
    const int tid = blockIdx.x * 256 + threadIdx.x;   // 262144
    const int qln = tid >> 4;          // 0..16383 = b*2048 + qr
    const int dq  = tid & 15;
    const int b   = qln >> 11;
    const int qr  = qln & 2047;

    const float2* ml2 = (const float2*)ML;
    const size_t MLS = (size_t)8 * SEQ;
    float2 mls[SPLIT];
#pragma unroll
    for (int s = 0; s < SPLIT; s++) mls[s] = ml2[(size_t)(s * 8 + b) * SEQ + qr];
    float mm = mls[0].x;
#pragma unroll
    for (int s = 1; s < SPLIT; s++) mm = fmaxf(mm, mls[s].x);
    float f[SPLIT], denom = 0.0f;
#pragma unroll
    for (int s = 0; s < SPLIT; s++) {
        f[s] = __expf(mls[s].x - mm);
        denom += mls[s].y * f[s];
    }
    float inv = 1.0f / denom;

    const size_t POS = (size_t)8 * SEQ * 64;
    const size_t o0  = ((size_t)b * SEQ + qr) * 64 + dq * 4;
    f32x4 acc = {0, 0, 0, 0};
#pragma unroll
    for (int s = 0; s < SPLIT; s++)
        acc += (*(const f32x4*)(PO + s * POS + o0)) * f[s];
    *(f32x4*)(O + ((size_t)b * SEQ + qr) * DIM + dq * 4) = acc * inv;
    (void)MLS;
}

extern "C" void kernel_launch(void* const* d_in, const int* in_sizes, int n_in,
                              void* d_out, int out_size, void* d_ws, size_t ws_size,
                              hipStream_t stream) {
    const float* Q  = (const float*)d_in[0];
    const float* K  = (const float*)d_in[1];
    const float* V  = (const float*)d_in[2];
    const float* MQ = (const float*)d_in[3];
    const float* MK = (const float*)d_in[4];
    const float* MV = (const float*)d_in[5];
    float* O = (float*)d_out;

    ushort* wsKV = (ushort*)d_ws;
    float*  PO   = (float*)((char*)d_ws + (4u << 20));
    float*  ML   = (float*)((char*)d_ws + (20u << 20));

    prep_kv  <<<dim3(256),  dim3(256), 0, stream>>>(K, V, MV, wsKV);
    attn_main<<<dim3(1024), dim3(256), 0, stream>>>(Q, MQ, MK, wsKV, PO, ML);
    merge_o  <<<dim3(1024), dim3(256), 0, stream>>>(PO, ML, O);
}